// Round 5
// baseline (126.284 us; speedup 1.0000x reference)
//
#include <hip/hip_runtime.h>
#include <cstdint>
#include <cstddef>

// ---------------------------------------------------------------------------
// MultiHeadExternalAttention, algebraically collapsed:
//   logits = x @ Wk   (Wk[e,hm] = sum_d W_in[e,h*128+d]*W_mk[d,m]) + bk
//   attn   = softmax_n(logits); attn /= (sum_m attn + 1e-9)
//   out    = attn @ Wv (Wv[hm,e] = sum_d W_mv[m,d]*W_out[h*128+d,e]) + bv
// B=32 N=1024 E=512 H=16 M=16 HM=256 ROWS=32768
// Round 5: barrier-free GEMMs — B-panel resident in LDS (staged once),
// A streamed global->register as MFMA fragments, depth-3 prefetch.
// ---------------------------------------------------------------------------

typedef unsigned short u16;
typedef unsigned int u32;
typedef short s16x8 __attribute__((ext_vector_type(8)));
typedef float f32x4 __attribute__((ext_vector_type(4)));

// workspace layout (bytes)
constexpr size_t OFF_BVP  = 0;                        // f32 [32][512] (64 KiB)
constexpr size_t OFF_WKT  = 1u << 20;                 // u16 [256][512]  (256 KiB)
constexpr size_t OFF_WVT  = OFF_WKT + (1u << 18);     // u16 [512][256]  (256 KiB)
constexpr size_t OFF_BK   = OFF_WVT + (1u << 18);     // f32 [256]
constexpr size_t OFF_BV   = OFF_BK + 4096;            // f32 [512]
constexpr size_t OFF_INV  = OFF_BV + 4096;            // f32 [32][256]
constexpr size_t OFF_PART = 2u << 20;                 // f32 [32][8][256]
constexpr size_t OFF_LOG  = 4u << 20;                 // u16 [32768][256] (16 MiB)
constexpr size_t OFF_P    = 20u << 20;                // u16 [32768][256] (16 MiB)

__device__ __forceinline__ float bf2f(u16 v) {
  union { u32 u; float f; } c; c.u = ((u32)v) << 16; return c.f;
}
__device__ __forceinline__ u16 f2bf(float f) {
  union { float f; u32 u; } c; c.f = f;
  u32 u = c.u;
  u += 0x7fffu + ((u >> 16) & 1u);
  return (u16)(u >> 16);
}
__device__ __forceinline__ uint4 pack_bf8(float4 lo, float4 hi) {
  return make_uint4((u32)f2bf(lo.x) | ((u32)f2bf(lo.y) << 16),
                    (u32)f2bf(lo.z) | ((u32)f2bf(lo.w) << 16),
                    (u32)f2bf(hi.x) | ((u32)f2bf(hi.y) << 16),
                    (u32)f2bf(hi.z) | ((u32)f2bf(hi.w) << 16));
}
__device__ __forceinline__ s16x8 as_s16x8(uint4 v) {
  union { uint4 u; s16x8 s; } c; c.u = v; return c.s;
}

__device__ __forceinline__ void mfma_bf16(f32x4& acc, s16x8 a, s16x8 b) {
  asm volatile("v_mfma_f32_16x16x32_bf16 %0, %1, %2, %0"
               : "+v"(acc) : "v"(a), "v"(b));
}

// ---------------------------------------------------------------------------
// WkT[hm][e] = sum_d W_in[e, h*128+d] * W_mk[d, m]   (stored transposed, bf16)
__global__ void prep_wkt(const float* __restrict__ wi, const float* __restrict__ wm,
                         u16* __restrict__ wkT) {
  const int gid = blockIdx.x * 256 + threadIdx.x;
  const int hm = gid & 255, e = gid >> 8;
  const int h = hm >> 4, m = hm & 15;
  float acc = 0.f;
  for (int d = 0; d < 128; d++)
    acc += wi[e * 2048 + h * 128 + d] * wm[d * 16 + m];
  wkT[hm * 512 + e] = f2bf(acc);
}

// WvT[e][hm] = sum_d W_mv[m,d] * W_out[h*128+d, e]
// one block per h; W_out rows streamed coalesced, W_mv in LDS.
__global__ __launch_bounds__(256) void prep_wvt(const float* __restrict__ mv,
                                                const float* __restrict__ wo,
                                                u16* __restrict__ wvT) {
  __shared__ float wmv[2048];  // 16 x 128
  const int h = blockIdx.x;    // 16
  const int t = threadIdx.x;   // 256
  for (int i = t; i < 2048; i += 256) wmv[i] = mv[i];
  __syncthreads();
  float acc0[16], acc1[16];
#pragma unroll
  for (int m = 0; m < 16; m++) { acc0[m] = 0.f; acc1[m] = 0.f; }
  for (int d = 0; d < 128; d++) {
    const float w0 = wo[(size_t)(h * 128 + d) * 512 + t];
    const float w1 = wo[(size_t)(h * 128 + d) * 512 + 256 + t];
#pragma unroll
    for (int m = 0; m < 16; m++) {
      const float c = wmv[m * 128 + d];
      acc0[m] += c * w0;
      acc1[m] += c * w1;
    }
  }
#pragma unroll
  for (int m = 0; m < 16; m++) {
    wvT[(size_t)t * 256 + h * 16 + m] = f2bf(acc0[m]);
    wvT[(size_t)(t + 256) * 256 + h * 16 + m] = f2bf(acc1[m]);
  }
}

// bk[hm] = b_mk[m] + sum_d b_in[h*128+d]*W_mk[d,m]
__global__ void prep_bk(const float* __restrict__ b_in, const float* __restrict__ wm,
                        const float* __restrict__ b_mk, float* __restrict__ bk) {
  const int t = threadIdx.x;
  const int h = t >> 4, m = t & 15;
  float acc = b_mk[m];
  for (int d = 0; d < 128; d++) acc += b_in[h * 128 + d] * wm[d * 16 + m];
  bk[t] = acc;
}

// bv partial: block k reduces 64 coalesced rows of W_out weighted by b_mv
__global__ void bv_part(const float* __restrict__ wo, const float* __restrict__ b_mv,
                        float* __restrict__ bvp) {
  const int k = blockIdx.x;   // 32
  const int t = threadIdx.x;  // 256
  float a0 = 0.f, a1 = 0.f;
  const int c0 = k * 64;
#pragma unroll 8
  for (int c = c0; c < c0 + 64; c++) {
    const float w = b_mv[c & 127];
    a0 += w * wo[(size_t)c * 512 + t];
    a1 += w * wo[(size_t)c * 512 + 256 + t];
  }
  bvp[k * 512 + t] = a0;
  bvp[k * 512 + 256 + t] = a1;
}

// bv[e] = b_out[e] + sum_k bvp[k][e]
__global__ void bv_fin(const float* __restrict__ bvp, const float* __restrict__ b_out,
                       float* __restrict__ bv) {
  const int e = blockIdx.x * 256 + threadIdx.x;  // 512
  float s = b_out[e];
#pragma unroll
  for (int k = 0; k < 32; k++) s += bvp[k * 512 + e];
  bv[e] = s;
}

// ---------------------------------------------------------------------------
// GEMM A: logits[32768,256] = x[32768,512] @ Wk + bk (bf16 out).
// Grid (2 colblk, 128 rowblk); block = 256 rows x 128 cols, 8 waves.
// Whole B-panel (128 cols x K512 bf16 = 128 KiB) in LDS, staged once.
// A: global fp32 -> reg -> pack bf16 = direct MFMA A-frags. No K-loop
// barriers; depth-3 prefetch, fully unrolled (static reg indices).
__global__ __launch_bounds__(512, 2) void gemm_a(const float* __restrict__ x,
                                                 const u16* __restrict__ wkT,
                                                 const float* __restrict__ bk,
                                                 u16* __restrict__ logits) {
  __shared__ u16 Bs[65536];  // cells [kg 0..63][col 0..127] of 8 bf16
  const int t = threadIdx.x;
  const int l = t & 63, w = t >> 6;
  const int lrow = l & 15, lkg = l >> 4;
  const int gCol0 = blockIdx.x << 7;
  const int gRow0 = blockIdx.y << 8;

  // stage B panel: 8192 cells, 16 per thread; consecutive threads ->
  // consecutive cols (conflict-free LDS writes; global 16B-grain reads
  // are L2-absorbed: wkT is 256 KiB total).
#pragma unroll
  for (int i = 0; i < 16; i++) {
    const int id = i * 512 + t;
    const int col = id & 127, kg = id >> 7;
    *(uint4*)&Bs[(kg * 128 + col) * 8] =
        *(const uint4*)(wkT + (size_t)(gCol0 + col) * 512 + kg * 8);
  }
  __syncthreads();

  f32x4 acc[2][8];
#pragma unroll
  for (int g = 0; g < 2; g++)
#pragma unroll
    for (int n = 0; n < 8; n++) acc[g][n] = f32x4{0.f, 0.f, 0.f, 0.f};

  // per-lane A pointer: row = gRow0 + w*32 + lrow (+ g*16), k = lkg*8 (+ kc*32)
  const float* aRow = x + (size_t)(gRow0 + w * 32 + lrow) * 512 + lkg * 8;

  float4 pa[3][2][2];
#pragma unroll
  for (int d = 0; d < 3; d++)
#pragma unroll
    for (int g = 0; g < 2; g++) {
      pa[d][g][0] = *(const float4*)(aRow + g * 8192 + d * 32);
      pa[d][g][1] = *(const float4*)(aRow + g * 8192 + d * 32 + 4);
    }

#pragma unroll
  for (int kc = 0; kc < 16; ++kc) {
    const int d = kc % 3;
    s16x8 af[2];
    af[0] = as_s16x8(pack_bf8(pa[d][0][0], pa[d][0][1]));
    af[1] = as_s16x8(pack_bf8(pa[d][1][0], pa[d][1][1]));
    if (kc + 3 < 16) {
#pragma unroll
      for (int g = 0; g < 2; g++) {
        pa[d][g][0] = *(const float4*)(aRow + g * 8192 + (kc + 3) * 32);
        pa[d][g][1] = *(const float4*)(aRow + g * 8192 + (kc + 3) * 32 + 4);
      }
    }
    const u16* bcell = &Bs[((kc * 4 + lkg) * 128 + lrow) * 8];
#pragma unroll
    for (int n = 0; n < 8; ++n) {
      const s16x8 bfr = *(const s16x8*)(bcell + n * 128);
      mfma_bf16(acc[0][n], af[0], bfr);
      mfma_bf16(acc[1][n], af[1], bfr);
    }
  }

  asm volatile("s_nop 7\n\ts_nop 7");
  const int crow = lkg * 4;
#pragma unroll
  for (int n = 0; n < 8; n++) {
    const int col = gCol0 + n * 16 + lrow;
    const float bias = bk[col];
#pragma unroll
    for (int g = 0; g < 2; g++) {
      const int row0 = gRow0 + w * 32 + g * 16 + crow;
#pragma unroll
      for (int j = 0; j < 4; j++)
        logits[(size_t)(row0 + j) * 256 + col] = f2bf(acc[g][n][j] + bias);
    }
  }
}

// per-(b,hm) partial sum of exp over 128-row chunk (no max needed: |logit|<~3)
__global__ __launch_bounds__(256) void colsum_part(const u16* __restrict__ logits,
                                                   float* __restrict__ part) {
  const int b = blockIdx.x, ch = blockIdx.y, hm = threadIdx.x;
  const u16* p = logits + ((size_t)(b * 1024 + ch * 128) * 256) + hm;
  float s = 0.f;
#pragma unroll 4
  for (int n = 0; n < 128; n++) s += __expf(bf2f(p[(size_t)n * 256]));
  part[(b * 8 + ch) * 256 + hm] = s;
}

__global__ void colsum_fin(const float* __restrict__ part, float* __restrict__ inv) {
  const int b = blockIdx.x, hm = threadIdx.x;
  float s = 0.f;
#pragma unroll
  for (int c = 0; c < 8; c++) s += part[(b * 8 + c) * 256 + hm];
  inv[b * 256 + hm] = 1.0f / s;
}

// P[r][hm] = exp(lg)*inv, L1-normalized per (row, head). 16 threads per row.
__global__ __launch_bounds__(256) void p_prep(const u16* __restrict__ lg,
                                              const float* __restrict__ inv,
                                              u16* __restrict__ P) {
  const int t = threadIdx.x;
  const int r = blockIdx.x * 16 + (t >> 4);
  const int h = t & 15;
  const int b = r >> 10;
  const u16* src = lg + (size_t)r * 256 + h * 16;
  uint4 q0 = *(const uint4*)src;
  uint4 q1 = *(const uint4*)(src + 8);
  const float* ivp = inv + b * 256 + h * 16;
  const u32 qq[8] = {q0.x, q0.y, q0.z, q0.w, q1.x, q1.y, q1.z, q1.w};
  float e[16];
#pragma unroll
  for (int p = 0; p < 8; p++) {
    e[p * 2]     = __expf(bf2f((u16)(qq[p] & 0xffffu))) * ivp[p * 2];
    e[p * 2 + 1] = __expf(bf2f((u16)(qq[p] >> 16)))     * ivp[p * 2 + 1];
  }
  float s = 0.f;
#pragma unroll
  for (int p = 0; p < 16; p++) s += e[p];
  const float rs = 1.0f / (s + 1e-9f);
  u32 pk[8];
#pragma unroll
  for (int p = 0; p < 8; p++)
    pk[p] = (u32)f2bf(e[p * 2] * rs) | ((u32)f2bf(e[p * 2 + 1] * rs) << 16);
  u16* dst = P + (size_t)r * 256 + h * 16;
  *(uint4*)dst = make_uint4(pk[0], pk[1], pk[2], pk[3]);
  *(uint4*)(dst + 8) = make_uint4(pk[4], pk[5], pk[6], pk[7]);
}

// ---------------------------------------------------------------------------
// GEMM B: out[32768,512] = P[32768,256] @ Wv + bv (fp32 out).
// Grid (4 colblk, 128 rowblk); block = 256 rows x 128 cols, 8 waves.
// B-panel (128 x K256 bf16 = 64 KiB) in LDS -> 2 blocks/CU. A (P, bf16)
// loads are direct MFMA frags (one uint4/lane). Depth-2 prefetch.
__global__ __launch_bounds__(512, 4) void gemm_b(const u16* __restrict__ P,
                                                 const u16* __restrict__ wvT,
                                                 const float* __restrict__ bvv,
                                                 float* __restrict__ out) {
  __shared__ u16 Bs[32768];  // cells [kg 0..31][col 0..127] of 8 bf16
  const int t = threadIdx.x;
  const int l = t & 63, w = t >> 6;
  const int lrow = l & 15, lkg = l >> 4;
  const int gCol0 = blockIdx.x << 7;
  const int gRow0 = blockIdx.y << 8;

#pragma unroll
  for (int i = 0; i < 8; i++) {
    const int id = i * 512 + t;
    const int col = id & 127, kg = id >> 7;
    *(uint4*)&Bs[(kg * 128 + col) * 8] =
        *(const uint4*)(wvT + (size_t)(gCol0 + col) * 256 + kg * 8);
  }
  __syncthreads();

  f32x4 acc[2][8];
#pragma unroll
  for (int g = 0; g < 2; g++)
#pragma unroll
    for (int n = 0; n < 8; n++) acc[g][n] = f32x4{0.f, 0.f, 0.f, 0.f};

  const u16* aRow = P + (size_t)(gRow0 + w * 32 + lrow) * 256 + lkg * 8;

  uint4 pa[2][2];
#pragma unroll
  for (int d = 0; d < 2; d++)
#pragma unroll
    for (int g = 0; g < 2; g++)
      pa[d][g] = *(const uint4*)(aRow + g * 4096 + d * 32);

#pragma unroll
  for (int kc = 0; kc < 8; ++kc) {
    const int d = kc & 1;
    s16x8 af[2];
    af[0] = as_s16x8(pa[d][0]);
    af[1] = as_s16x8(pa[d][1]);
    if (kc + 2 < 8) {
#pragma unroll
      for (int g = 0; g < 2; g++)
        pa[d][g] = *(const uint4*)(aRow + g * 4096 + (kc + 2) * 32);
    }
    const u16* bcell = &Bs[((kc * 4 + lkg) * 128 + lrow) * 8];
#pragma unroll
    for (int n = 0; n < 8; ++n) {
      const s16x8 bfr = *(const s16x8*)(bcell + n * 128);
      mfma_bf16(acc[0][n], af[0], bfr);
      mfma_bf16(acc[1][n], af[1], bfr);
    }
  }

  asm volatile("s_nop 7\n\ts_nop 7");
  const int crow = lkg * 4;
#pragma unroll
  for (int n = 0; n < 8; n++) {
    const int col = gCol0 + n * 16 + lrow;
    const float bias = bvv[col];
#pragma unroll
    for (int g = 0; g < 2; g++) {
      const int row0 = gRow0 + w * 32 + g * 16 + crow;
#pragma unroll
      for (int j = 0; j < 4; j++)
        out[(size_t)(row0 + j) * 512 + col] = acc[g][n][j] + bias;
    }
  }
}

// ---------------------------------------------------------------------------
extern "C" void kernel_launch(void* const* d_in, const int* in_sizes, int n_in,
                              void* d_out, int out_size, void* d_ws, size_t ws_size,
                              hipStream_t stream) {
  (void)in_sizes; (void)n_in; (void)out_size; (void)ws_size;
  const float* x     = (const float*)d_in[0];
  const float* W_in  = (const float*)d_in[1];
  const float* b_in  = (const float*)d_in[2];
  const float* W_mk  = (const float*)d_in[3];
  const float* b_mk  = (const float*)d_in[4];
  const float* W_mv  = (const float*)d_in[5];
  const float* b_mv  = (const float*)d_in[6];
  const float* W_out = (const float*)d_in[7];
  const float* b_out = (const float*)d_in[8];

  char* ws = (char*)d_ws;
  float* bvp  = (float*)(ws + OFF_BVP);
  u16*   wkT  = (u16*)(ws + OFF_WKT);
  u16*   wvT  = (u16*)(ws + OFF_WVT);
  float* bk   = (float*)(ws + OFF_BK);
  float* bv   = (float*)(ws + OFF_BV);
  float* inv  = (float*)(ws + OFF_INV);
  float* part = (float*)(ws + OFF_PART);
  u16*   lg   = (u16*)(ws + OFF_LOG);
  u16*   Pm   = (u16*)(ws + OFF_P);
  float* outp = (float*)d_out;

  prep_wkt<<<512, 256, 0, stream>>>(W_in, W_mk, wkT);
  prep_wvt<<<16, 256, 0, stream>>>(W_mv, W_out, wvT);
  prep_bk<<<1, 256, 0, stream>>>(b_in, W_mk, b_mk, bk);
  bv_part<<<32, 256, 0, stream>>>(W_out, b_mv, bvp);
  bv_fin<<<2, 256, 0, stream>>>(bvp, b_out, bv);
  gemm_a<<<dim3(2, 128), 512, 0, stream>>>(x, wkT, bk, lg);
  colsum_part<<<dim3(32, 8), 256, 0, stream>>>(lg, part);
  colsum_fin<<<32, 256, 0, stream>>>(part, inv);
  p_prep<<<2048, 256, 0, stream>>>(lg, inv, Pm);
  gemm_b<<<dim3(4, 128), 512, 0, stream>>>(Pm, wvT, bv, outp);
}

// Round 6
// 89.535 us; speedup vs baseline: 1.4105x; 1.4105x over previous
//
#include <hip/hip_runtime.h>
#include <cstdint>
#include <cstddef>

// ---------------------------------------------------------------------------
// MultiHeadExternalAttention, algebraically collapsed:
//   logits = x @ Wk   (Wk[e,hm] = sum_d W_in[e,h*128+d]*W_mk[d,m]) + bk
//   attn   = softmax_n(logits); attn /= (sum_m attn + 1e-9)
//   out    = attn @ Wv (Wv[hm,e] = sum_d W_mv[m,d]*W_out[h*128+d,e]) + bv
// B=32 N=1024 E=512 H=16 M=16 HM=256 ROWS=32768
// Round 6: prep_wvt -> 128-block partial-K (bv folded in); gemm_a pack via
// v_cvt_pk_bf16_f32; colsum fused into gemm_a epilogue.
// ---------------------------------------------------------------------------

typedef unsigned short u16;
typedef unsigned int u32;
typedef short s16x8 __attribute__((ext_vector_type(8)));
typedef float f32x4 __attribute__((ext_vector_type(4)));

// workspace layout (bytes)
constexpr size_t OFF_WKT  = 1u << 20;                 // u16 [256][512]  (256 KiB)
constexpr size_t OFF_WVT  = OFF_WKT + (1u << 18);     // u16 [512][256]  (256 KiB)
constexpr size_t OFF_BK   = OFF_WVT + (1u << 18);     // f32 [256]
constexpr size_t OFF_BV   = OFF_BK + 4096;            // f32 [512]
constexpr size_t OFF_INV  = OFF_BV + 4096;            // f32 [32][256]
constexpr size_t OFF_CP   = 2u << 20;                 // f32 [128][256] colsum partials
constexpr size_t OFF_LOG  = 4u << 20;                 // u16 [32768][256] (16 MiB)
constexpr size_t OFF_P    = 20u << 20;                // u16 [32768][256] (16 MiB)
constexpr size_t OFF_WVP  = 40u << 20;                // f32 [128][512][16] (4 MiB)
constexpr size_t OFF_BVP  = 45u << 20;                // f32 [128][512] (256 KiB)

__device__ __forceinline__ float bf2f(u16 v) {
  union { u32 u; float f; } c; c.u = ((u32)v) << 16; return c.f;
}
__device__ __forceinline__ u16 f2bf(float f) {
  union { float f; u32 u; } c; c.f = f;
  u32 u = c.u;
  u += 0x7fffu + ((u >> 16) & 1u);
  return (u16)(u >> 16);
}
// packed RNE f32x2 -> bf16x2 (single HW op; no builtin on gfx950)
__device__ __forceinline__ u32 cvt2(float lo, float hi) {
  u32 r;
  asm("v_cvt_pk_bf16_f32 %0, %1, %2" : "=v"(r) : "v"(lo), "v"(hi));
  return r;
}
__device__ __forceinline__ uint4 pack_bf8(float4 lo, float4 hi) {
  return make_uint4(cvt2(lo.x, lo.y), cvt2(lo.z, lo.w),
                    cvt2(hi.x, hi.y), cvt2(hi.z, hi.w));
}
__device__ __forceinline__ s16x8 as_s16x8(uint4 v) {
  union { uint4 u; s16x8 s; } c; c.u = v; return c.s;
}

__device__ __forceinline__ void mfma_bf16(f32x4& acc, s16x8 a, s16x8 b) {
  asm volatile("v_mfma_f32_16x16x32_bf16 %0, %1, %2, %0"
               : "+v"(acc) : "v"(a), "v"(b));
}

// ---------------------------------------------------------------------------
// WkT[hm][e] = sum_d W_in[e, h*128+d] * W_mk[d, m]   (stored transposed, bf16)
__global__ void prep_wkt(const float* __restrict__ wi, const float* __restrict__ wm,
                         u16* __restrict__ wkT) {
  const int gid = blockIdx.x * 256 + threadIdx.x;
  const int hm = gid & 255, e = gid >> 8;
  const int h = hm >> 4, m = hm & 15;
  float acc = 0.f;
  for (int d = 0; d < 128; d++)
    acc += wi[e * 2048 + h * 128 + d] * wm[d * 16 + m];
  wkT[hm * 512 + e] = f2bf(acc);
}

// wvt partial: block = (h, dc); 16 d's per chunk; coalesced W_out rows.
// wvp[(h*8+dc)][e][m] = sum_{d in chunk} W_mv[m,d]*W_out[h*128+d, e]
// bvp[(h*8+dc)][e]    = sum_{d in chunk} b_mv[d]  *W_out[h*128+d, e]
__global__ __launch_bounds__(256) void wvt_part(const float* __restrict__ mv,
                                                const float* __restrict__ b_mv,
                                                const float* __restrict__ wo,
                                                float* __restrict__ wvp,
                                                float* __restrict__ bvp) {
  __shared__ float wmv_l[16][16];
  __shared__ float bmv_l[16];
  const int blk = blockIdx.x;        // 0..127
  const int h = blk >> 3, dc = blk & 7;
  const int t = threadIdx.x;         // 256
  {
    const int m = t >> 4, dd = t & 15;
    wmv_l[m][dd] = mv[m * 128 + dc * 16 + dd];
    if (t < 16) bmv_l[t] = b_mv[dc * 16 + t];
  }
  __syncthreads();
  float acc0[16], acc1[16];
  float bv0 = 0.f, bv1 = 0.f;
#pragma unroll
  for (int m = 0; m < 16; m++) { acc0[m] = 0.f; acc1[m] = 0.f; }
#pragma unroll
  for (int dd = 0; dd < 16; dd++) {
    const float w0 = wo[(size_t)(h * 128 + dc * 16 + dd) * 512 + t];
    const float w1 = wo[(size_t)(h * 128 + dc * 16 + dd) * 512 + 256 + t];
#pragma unroll
    for (int m = 0; m < 16; m++) {
      const float c = wmv_l[m][dd];
      acc0[m] += c * w0;
      acc1[m] += c * w1;
    }
    bv0 += bmv_l[dd] * w0;
    bv1 += bmv_l[dd] * w1;
  }
  float* w0p = wvp + ((size_t)blk * 512 + t) * 16;
  float* w1p = wvp + ((size_t)blk * 512 + 256 + t) * 16;
#pragma unroll
  for (int m = 0; m < 16; m++) { w0p[m] = acc0[m]; w1p[m] = acc1[m]; }
  bvp[(size_t)blk * 512 + t] = bv0;
  bvp[(size_t)blk * 512 + 256 + t] = bv1;
}

// wvT[e][hm] = f2bf(sum_dc wvp); bv[e] = b_out[e] + sum_blk bvp
__global__ __launch_bounds__(256) void wvt_fin(const float* __restrict__ wvp,
                                               const float* __restrict__ bvp,
                                               const float* __restrict__ b_out,
                                               u16* __restrict__ wvT,
                                               float* __restrict__ bv) {
  const int e = blockIdx.x;   // 512
  const int t = threadIdx.x;  // 256 = hm
  const int h = t >> 4, m = t & 15;
  float s = 0.f;
#pragma unroll
  for (int dc = 0; dc < 8; dc++)
    s += wvp[((size_t)(h * 8 + dc) * 512 + e) * 16 + m];
  wvT[(size_t)e * 256 + t] = f2bf(s);
  if (t < 64) {
    float b = bvp[(size_t)t * 512 + e] + bvp[(size_t)(t + 64) * 512 + e];
#pragma unroll
    for (int mask = 32; mask >= 1; mask >>= 1) b += __shfl_xor(b, mask);
    if (t == 0) bv[e] = b_out[e] + b;
  }
}

// bk[hm] = b_mk[m] + sum_d b_in[h*128+d]*W_mk[d,m]
__global__ void prep_bk(const float* __restrict__ b_in, const float* __restrict__ wm,
                        const float* __restrict__ b_mk, float* __restrict__ bk) {
  const int t = threadIdx.x;
  const int h = t >> 4, m = t & 15;
  float acc = b_mk[m];
  for (int d = 0; d < 128; d++) acc += b_in[h * 128 + d] * wm[d * 16 + m];
  bk[t] = acc;
}

// ---------------------------------------------------------------------------
// GEMM A: logits[32768,256] = x[32768,512] @ Wk + bk (bf16 out) + fused
// per-block colsum-of-exp partials. Grid (2 colblk, 128 rowblk);
// block = 256 rows x 128 cols, 8 waves. B-panel (128 KiB) LDS-resident.
// A: global fp32 -> cvt_pk bf16 = direct MFMA frags; depth-3 prefetch,
// no K-loop barriers.
__global__ __launch_bounds__(512, 2) void gemm_a(const float* __restrict__ x,
                                                 const u16* __restrict__ wkT,
                                                 const float* __restrict__ bk,
                                                 u16* __restrict__ logits,
                                                 float* __restrict__ cpart) {
  __shared__ u16 Bs[65536];  // cells [kg 0..63][col 0..127] of 8 bf16
  __shared__ float CpL[8][128];
  const int t = threadIdx.x;
  const int l = t & 63, w = t >> 6;
  const int lrow = l & 15, lkg = l >> 4;
  const int gCol0 = blockIdx.x << 7;
  const int gRow0 = blockIdx.y << 8;

#pragma unroll
  for (int i = 0; i < 16; i++) {
    const int id = i * 512 + t;
    const int col = id & 127, kg = id >> 7;
    *(uint4*)&Bs[(kg * 128 + col) * 8] =
        *(const uint4*)(wkT + (size_t)(gCol0 + col) * 512 + kg * 8);
  }
  __syncthreads();

  f32x4 acc[2][8];
#pragma unroll
  for (int g = 0; g < 2; g++)
#pragma unroll
    for (int n = 0; n < 8; n++) acc[g][n] = f32x4{0.f, 0.f, 0.f, 0.f};

  const float* aRow = x + (size_t)(gRow0 + w * 32 + lrow) * 512 + lkg * 8;

  float4 pa[3][2][2];
#pragma unroll
  for (int d = 0; d < 3; d++)
#pragma unroll
    for (int g = 0; g < 2; g++) {
      pa[d][g][0] = *(const float4*)(aRow + g * 8192 + d * 32);
      pa[d][g][1] = *(const float4*)(aRow + g * 8192 + d * 32 + 4);
    }

#pragma unroll
  for (int kc = 0; kc < 16; ++kc) {
    const int d = kc % 3;
    s16x8 af[2];
    af[0] = as_s16x8(pack_bf8(pa[d][0][0], pa[d][0][1]));
    af[1] = as_s16x8(pack_bf8(pa[d][1][0], pa[d][1][1]));
    if (kc + 3 < 16) {
#pragma unroll
      for (int g = 0; g < 2; g++) {
        pa[d][g][0] = *(const float4*)(aRow + g * 8192 + (kc + 3) * 32);
        pa[d][g][1] = *(const float4*)(aRow + g * 8192 + (kc + 3) * 32 + 4);
      }
    }
    const u16* bcell = &Bs[((kc * 4 + lkg) * 128 + lrow) * 8];
#pragma unroll
    for (int n = 0; n < 8; ++n) {
      const s16x8 bfr = *(const s16x8*)(bcell + n * 128);
      mfma_bf16(acc[0][n], af[0], bfr);
      mfma_bf16(acc[1][n], af[1], bfr);
    }
  }

  asm volatile("s_nop 7\n\ts_nop 7");
  const int crow = lkg * 4;
  float esum[8];
#pragma unroll
  for (int n = 0; n < 8; n++) {
    const int col = gCol0 + n * 16 + lrow;
    const float bias = bk[col];
    float es = 0.f;
#pragma unroll
    for (int g = 0; g < 2; g++) {
      const int row0 = gRow0 + w * 32 + g * 16 + crow;
#pragma unroll
      for (int j = 0; j < 4; j++) {
        const u16 bq = f2bf(acc[g][n][j] + bias);
        logits[(size_t)(row0 + j) * 256 + col] = bq;
        es += __expf(bf2f(bq));
      }
    }
    esum[n] = es;
  }
  // reduce esum over the 4 lkg lane-groups (lanes l, l^16, l^32 share cols)
#pragma unroll
  for (int n = 0; n < 8; n++) {
    esum[n] += __shfl_xor(esum[n], 16);
    esum[n] += __shfl_xor(esum[n], 32);
  }
  if (l < 16) {
#pragma unroll
    for (int n = 0; n < 8; n++) CpL[w][n * 16 + l] = esum[n];
  }
  __syncthreads();
  if (t < 128) {
    float s = 0.f;
#pragma unroll
    for (int ww = 0; ww < 8; ww++) s += CpL[ww][t];
    cpart[(size_t)blockIdx.y * 256 + gCol0 + t] = s;
  }
}

// inv[b][hm] = 1 / sum over the batch's 4 row-block partials
__global__ void colsum_fin(const float* __restrict__ cpart, float* __restrict__ inv) {
  const int b = blockIdx.x, hm = threadIdx.x;
  float s = 0.f;
#pragma unroll
  for (int k = 0; k < 4; k++) s += cpart[(size_t)(b * 4 + k) * 256 + hm];
  inv[b * 256 + hm] = 1.0f / s;
}

// P[r][hm] = exp(lg)*inv, L1-normalized per (row, head). 16 threads per row.
__global__ __launch_bounds__(256) void p_prep(const u16* __restrict__ lg,
                                              const float* __restrict__ inv,
                                              u16* __restrict__ P) {
  const int t = threadIdx.x;
  const int r = blockIdx.x * 16 + (t >> 4);
  const int h = t & 15;
  const int b = r >> 10;
  const u16* src = lg + (size_t)r * 256 + h * 16;
  uint4 q0 = *(const uint4*)src;
  uint4 q1 = *(const uint4*)(src + 8);
  const float* ivp = inv + b * 256 + h * 16;
  const u32 qq[8] = {q0.x, q0.y, q0.z, q0.w, q1.x, q1.y, q1.z, q1.w};
  float e[16];
#pragma unroll
  for (int p = 0; p < 8; p++) {
    e[p * 2]     = __expf(bf2f((u16)(qq[p] & 0xffffu))) * ivp[p * 2];
    e[p * 2 + 1] = __expf(bf2f((u16)(qq[p] >> 16)))     * ivp[p * 2 + 1];
  }
  float s = 0.f;
#pragma unroll
  for (int p = 0; p < 16; p++) s += e[p];
  const float rs = 1.0f / (s + 1e-9f);
  u32 pk[8];
#pragma unroll
  for (int p = 0; p < 8; p++) pk[p] = cvt2(e[p * 2] * rs, e[p * 2 + 1] * rs);
  u16* dst = P + (size_t)r * 256 + h * 16;
  *(uint4*)dst = make_uint4(pk[0], pk[1], pk[2], pk[3]);
  *(uint4*)(dst + 8) = make_uint4(pk[4], pk[5], pk[6], pk[7]);
}

// ---------------------------------------------------------------------------
// GEMM B: out[32768,512] = P[32768,256] @ Wv + bv (fp32 out).
// Grid (4 colblk, 128 rowblk); block = 256 rows x 128 cols, 8 waves.
// B-panel (64 KiB) LDS-resident -> 2 blocks/CU. A loads = direct MFMA frags.
__global__ __launch_bounds__(512, 4) void gemm_b(const u16* __restrict__ P,
                                                 const u16* __restrict__ wvT,
                                                 const float* __restrict__ bvv,
                                                 float* __restrict__ out) {
  __shared__ u16 Bs[32768];  // cells [kg 0..31][col 0..127] of 8 bf16
  const int t = threadIdx.x;
  const int l = t & 63, w = t >> 6;
  const int lrow = l & 15, lkg = l >> 4;
  const int gCol0 = blockIdx.x << 7;
  const int gRow0 = blockIdx.y << 8;

#pragma unroll
  for (int i = 0; i < 8; i++) {
    const int id = i * 512 + t;
    const int col = id & 127, kg = id >> 7;
    *(uint4*)&Bs[(kg * 128 + col) * 8] =
        *(const uint4*)(wvT + (size_t)(gCol0 + col) * 256 + kg * 8);
  }
  __syncthreads();

  f32x4 acc[2][8];
#pragma unroll
  for (int g = 0; g < 2; g++)
#pragma unroll
    for (int n = 0; n < 8; n++) acc[g][n] = f32x4{0.f, 0.f, 0.f, 0.f};

  const u16* aRow = P + (size_t)(gRow0 + w * 32 + lrow) * 256 + lkg * 8;

  uint4 pa[2][2];
#pragma unroll
  for (int d = 0; d < 2; d++)
#pragma unroll
    for (int g = 0; g < 2; g++)
      pa[d][g] = *(const uint4*)(aRow + g * 4096 + d * 32);

#pragma unroll
  for (int kc = 0; kc < 8; ++kc) {
    const int d = kc & 1;
    s16x8 af[2];
    af[0] = as_s16x8(pa[d][0]);
    af[1] = as_s16x8(pa[d][1]);
    if (kc + 2 < 8) {
#pragma unroll
      for (int g = 0; g < 2; g++)
        pa[d][g] = *(const uint4*)(aRow + g * 4096 + (kc + 2) * 32);
    }
    const u16* bcell = &Bs[((kc * 4 + lkg) * 128 + lrow) * 8];
#pragma unroll
    for (int n = 0; n < 8; ++n) {
      const s16x8 bfr = *(const s16x8*)(bcell + n * 128);
      mfma_bf16(acc[0][n], af[0], bfr);
      mfma_bf16(acc[1][n], af[1], bfr);
    }
  }

  asm volatile("s_nop 7\n\ts_nop 7");
  const int crow = lkg * 4;
#pragma unroll
  for (int n = 0; n < 8; n++) {
    const int col = gCol0 + n * 16 + lrow;
    const float bias = bvv[col];
#pragma unroll
    for (int g = 0; g < 2; g++) {
      const int row0 = gRow0 + w * 32 + g * 16 + crow;
#pragma unroll
      for (int j = 0; j < 4; j++)
        out[(size_t)(row0 + j) * 512 + col] = acc[g][n][j] + bias;
    }
  }
}

// ---------------------------------------------------------------------------
extern "C" void kernel_launch(void* const* d_in, const int* in_sizes, int n_in,
                              void* d_out, int out_size, void* d_ws, size_t ws_size,
                              hipStream_t stream) {
  (void)in_sizes; (void)n_in; (void)out_size; (void)ws_size;
  const float* x     = (const float*)d_in[0];
  const float* W_in  = (const float*)d_in[1];
  const float* b_in  = (const float*)d_in[2];
  const float* W_mk  = (const float*)d_in[3];
  const float* b_mk  = (const float*)d_in[4];
  const float* W_mv  = (const float*)d_in[5];
  const float* b_mv  = (const float*)d_in[6];
  const float* W_out = (const float*)d_in[7];
  const float* b_out = (const float*)d_in[8];

  char* ws = (char*)d_ws;
  u16*   wkT  = (u16*)(ws + OFF_WKT);
  u16*   wvT  = (u16*)(ws + OFF_WVT);
  float* bk   = (float*)(ws + OFF_BK);
  float* bv   = (float*)(ws + OFF_BV);
  float* inv  = (float*)(ws + OFF_INV);
  float* cp   = (float*)(ws + OFF_CP);
  u16*   lg   = (u16*)(ws + OFF_LOG);
  u16*   Pm   = (u16*)(ws + OFF_P);
  float* wvp  = (float*)(ws + OFF_WVP);
  float* bvp  = (float*)(ws + OFF_BVP);
  float* outp = (float*)d_out;

  prep_wkt<<<512, 256, 0, stream>>>(W_in, W_mk, wkT);
  wvt_part<<<128, 256, 0, stream>>>(W_mv, b_mv, W_out, wvp, bvp);
  wvt_fin<<<512, 256, 0, stream>>>(wvp, bvp, b_out, wvT, bv);
  prep_bk<<<1, 256, 0, stream>>>(b_in, W_mk, b_mk, bk);
  gemm_a<<<dim3(2, 128), 512, 0, stream>>>(x, wkT, bk, lg, cp);
  colsum_fin<<<32, 256, 0, stream>>>(cp, inv);
  p_prep<<<2048, 256, 0, stream>>>(lg, inv, Pm);
  gemm_b<<<dim3(4, 128), 512, 0, stream>>>(Pm, wvT, bv, outp);
}